// Round 10
// baseline (1301.147 us; speedup 1.0000x reference)
//
#include <hip/hip_runtime.h>

#define HID 128
#define G3  384   // 3*HID
#define TSTEPS 5
#define BSHIFT 9          // 512 nodes per bucket
#define BNODES (1 << BSHIFT)
#define MAXBUK 256        // supports N up to 128k
#define PART_EPB 8192     // edges per k_part block

typedef unsigned int  uint;
typedef unsigned short ushort;

typedef float  f32x4  __attribute__((ext_vector_type(4)));
typedef __bf16 bf16x8 __attribute__((ext_vector_type(8)));

union B8u { uint4 u; bf16x8 b; ushort s[8]; };

static __device__ inline ushort f2bf(float f) {
  uint u = __float_as_uint(f);
  uint r = u + 0x7fffu + ((u >> 16) & 1u);   // RTN-even
  return (ushort)(r >> 16);
}
static __device__ inline float bf2f(ushort s) {
  return __uint_as_float(((uint)s) << 16);
}

// ---- once per call: W_comb = W_ih @ W_e (bf16), bvec = W_ih @ b_e, W_hh -> bf16
__global__ __launch_bounds__(128) void k_weights(
    const float* __restrict__ W_e, const float* __restrict__ b_e,
    const float* __restrict__ W_ih, const float* __restrict__ W_hh,
    ushort* __restrict__ Wcomb, ushort* __restrict__ Whh16, float* __restrict__ bvec,
    ushort* __restrict__ Wc0, ushort* __restrict__ Wh0)
{
  int j = blockIdx.x, t = threadIdx.x;
  if (j < G3) {
    __shared__ float row[HID];
    row[t] = W_ih[j * HID + t];
    __syncthreads();
    float acc = 0.f;
    for (int k = 0; k < HID; ++k) acc = fmaf(row[k], W_e[k * HID + t], acc);
    Wcomb[j * HID + t] = f2bf(acc);
    if (t == 0) {
      Wc0[j] = f2bf(acc);
      float b = 0.f;
      for (int k = 0; k < HID; ++k) b += row[k] * b_e[k];
      bvec[j] = b;
    }
  } else {
    int j2 = j - G3;
    Whh16[j2 * HID + t] = f2bf(W_hh[j2 * HID + t]);
    if (t == 0) Wh0[j2] = f2bf(W_hh[j2 * HID]);
  }
}

// ---- CSR build, stage 1: bucket histogram of dst (LDS-aggregated)
__global__ __launch_bounds__(256) void k_bh(const int* __restrict__ dst,
                                            int* __restrict__ bhist, int E) {
  __shared__ int lh[MAXBUK];
  int t = threadIdx.x;
  if (t < MAXBUK) lh[t] = 0;
  __syncthreads();
  for (int e = blockIdx.x * 256 + t; e < E; e += gridDim.x * 256)
    atomicAdd(&lh[dst[e] >> BSHIFT], 1);
  __syncthreads();
  if (t < MAXBUK && lh[t]) atomicAdd(&bhist[t], lh[t]);
}

// ---- stage 2: serial scan of <=256 bucket counts (trivial size)
__global__ __launch_bounds__(256) void k_bsc(const int* __restrict__ bhist,
                                             int* __restrict__ bbase,
                                             int* __restrict__ gcur,
                                             int* __restrict__ rowptr, int E, int N) {
  __shared__ int ls[MAXBUK];
  int t = threadIdx.x;
  ls[t] = bhist[t];
  __syncthreads();
  if (t == 0) {
    int run = 0;
    for (int i = 0; i < MAXBUK; ++i) {
      bbase[i] = run; gcur[i] = run; run += ls[i];
    }
    bbase[MAXBUK] = run;
    rowptr[N] = E;
  }
}

// ---- stage 3: partition packed (dl<<20)|src into bucket-grouped ebuf.
__global__ __launch_bounds__(256) void k_part(
    const int* __restrict__ src, const int* __restrict__ dst,
    int* __restrict__ gcur, uint* __restrict__ ebuf, int E) {
  __shared__ int lh[MAXBUK], lbase[MAXBUK], lcur[MAXBUK];
  int t = threadIdx.x;
  int base = blockIdx.x * PART_EPB;
  if (t < MAXBUK) lh[t] = 0;
  __syncthreads();
#pragma unroll 4
  for (int j = 0; j < PART_EPB / 256; ++j) {
    int e = base + j * 256 + t;
    if (e < E) atomicAdd(&lh[dst[e] >> BSHIFT], 1);
  }
  __syncthreads();
  if (t < MAXBUK) {
    lbase[t] = lh[t] ? atomicAdd(&gcur[t], lh[t]) : 0;
    lcur[t] = 0;
  }
  __syncthreads();
#pragma unroll 4
  for (int j = 0; j < PART_EPB / 256; ++j) {
    int e = base + j * 256 + t;
    if (e < E) {
      int d = dst[e];
      int b = d >> BSHIFT;
      int p = atomicAdd(&lcur[b], 1);
      ebuf[lbase[b] + p] = (uint)src[e] | ((uint)(d & (BNODES - 1)) << 20);
    }
  }
}

// ---- stage 4: one block per bucket: LDS hist -> scan -> rowptr/deg -> scatter
__global__ __launch_bounds__(256) void k_fill2(
    const uint* __restrict__ ebuf, const int* __restrict__ bbase,
    int* __restrict__ csrc, int* __restrict__ rowptr, int* __restrict__ deg, int N) {
  __shared__ int hcnt[BNODES];
  __shared__ int wls[4];
  int t = threadIdx.x;
  int b = blockIdx.x;
  int ebeg = bbase[b], eend = bbase[b + 1];
  for (int i = t; i < BNODES; i += 256) hcnt[i] = 0;
  __syncthreads();
  for (int e = ebeg + t; e < eend; e += 256)
    atomicAdd(&hcnt[ebuf[e] >> 20], 1);
  __syncthreads();
  const int PER = BNODES / 256;
  int lane = t & 63, wv = t >> 6;
  int x[PER]; int s = 0;
#pragma unroll
  for (int i = 0; i < PER; ++i) { x[i] = hcnt[PER * t + i]; s += x[i]; }
  int incl = s;
#pragma unroll
  for (int off = 1; off < 64; off <<= 1) {
    int u = __shfl_up(incl, off, 64);
    if (lane >= off) incl += u;
  }
  if (lane == 63) wls[wv] = incl;
  __syncthreads();
  int wbase = 0;
  for (int i = 0; i < wv; ++i) wbase += wls[i];
  int run = wbase + incl - s;
#pragma unroll
  for (int i = 0; i < PER; ++i) {
    int node = (b << BSHIFT) + PER * t + i;
    hcnt[PER * t + i] = run;
    if (node < N) { rowptr[node] = ebeg + run; deg[node] = x[i]; }
    run += x[i];
  }
  __syncthreads();
  for (int e = ebeg + t; e < eend; e += 256) {
    uint v = ebuf[e];
    int p = atomicAdd(&hcnt[v >> 20], 1);
    csrc[ebeg + p] = (int)(v & 0xFFFFFu);
  }
}

// ---- m16[v] = bf16(m[v]) — the only nonzero column of h at t=0
__global__ void k_minit(const float* __restrict__ m, ushort* __restrict__ m16, int N) {
  int v = blockIdx.x * 256 + threadIdx.x;
  if (v < N) m16[v] = f2bf(m[v]);
}

// ---- step-0 gather: h rows are [m,0,...,0] so only dim 0 needs summing.
__global__ __launch_bounds__(256) void k_gather0(
    const int* __restrict__ rowptr, const int* __restrict__ csrc,
    const ushort* __restrict__ m16, ushort* __restrict__ hsum0, int N)
{
  int v = blockIdx.x * 256 + threadIdx.x;
  if (v >= N) return;
  int beg = rowptr[v], end = rowptr[v + 1];
  float a0 = 0.f, a1 = 0.f, a2 = 0.f, a3 = 0.f;
  int e = beg;
  for (; e + 16 <= end; e += 16) {
    a0 += (bf2f(m16[csrc[e + 0]]) + bf2f(m16[csrc[e + 4]])) +
          (bf2f(m16[csrc[e + 8]]) + bf2f(m16[csrc[e + 12]]));
    a1 += (bf2f(m16[csrc[e + 1]]) + bf2f(m16[csrc[e + 5]])) +
          (bf2f(m16[csrc[e + 9]]) + bf2f(m16[csrc[e + 13]]));
    a2 += (bf2f(m16[csrc[e + 2]]) + bf2f(m16[csrc[e + 6]])) +
          (bf2f(m16[csrc[e + 10]]) + bf2f(m16[csrc[e + 14]]));
    a3 += (bf2f(m16[csrc[e + 3]]) + bf2f(m16[csrc[e + 7]])) +
          (bf2f(m16[csrc[e + 11]]) + bf2f(m16[csrc[e + 15]]));
  }
  for (; e < end; e += 4) {
    if (e + 0 < end) a0 += bf2f(m16[csrc[e + 0]]);
    if (e + 1 < end) a1 += bf2f(m16[csrc[e + 1]]);
    if (e + 2 < end) a2 += bf2f(m16[csrc[e + 2]]);
    if (e + 3 < end) a3 += bf2f(m16[csrc[e + 3]]);
  }
  hsum0[v] = f2bf((a0 + a1) + (a2 + a3));
}

// ---- step-0 GRU: both GEMMs are rank-1 (only k=0 of A/H nonzero).
__global__ __launch_bounds__(256) void k_gru0(
    const ushort* __restrict__ hsum0, const ushort* __restrict__ m16,
    const int* __restrict__ deg,
    const ushort* __restrict__ Wc0, const ushort* __restrict__ Wh0,
    const float* __restrict__ bvec, const float* __restrict__ b_ih,
    const float* __restrict__ b_hh, ushort* __restrict__ hbn, int N)
{
  int idx = blockIdx.x * 256 + threadIdx.x;
  if (idx >= N * HID) return;
  int n = idx >> 7, d = idx & (HID - 1);
  float s0 = bf2f(hsum0[n]);
  float h0 = bf2f(m16[n]);
  float degf = (float)deg[n];
  float acc0 = s0 * bf2f(Wc0[d]);
  float acc1 = s0 * bf2f(Wc0[d + 128]);
  float acc2 = s0 * bf2f(Wc0[d + 256]);
  float acc3 = h0 * bf2f(Wh0[d]);
  float acc4 = h0 * bf2f(Wh0[d + 128]);
  float acc5 = h0 * bf2f(Wh0[d + 256]);
  float hold = (d == 0) ? h0 : 0.f;
  float ir = acc0 + degf * bvec[d] + b_ih[d];
  float iz = acc1 + degf * bvec[d + 128] + b_ih[d + 128];
  float in_ = acc2 + degf * bvec[d + 256] + b_ih[d + 256];
  float hr = acc3 + b_hh[d];
  float hz = acc4 + b_hh[d + 128];
  float hn = acc5 + b_hh[d + 256];
  float r = __builtin_amdgcn_rcpf(1.f + __expf(-(ir + hr)));
  float z = __builtin_amdgcn_rcpf(1.f + __expf(-(iz + hz)));
  float x2 = in_ + r * hn;
  float e2 = __expf(2.f * x2);
  float nv = 1.f - 2.f * __builtin_amdgcn_rcpf(e2 + 1.f);   // tanh
  float hv = (1.f - z) * nv + z * hold;
  hbn[idx] = f2bf(hv);
}

// ---- shared accumulate core (R8 semantics: 16-chunks tree + batched tail)
static __device__ __forceinline__ void accum_range(
    const ushort* __restrict__ hb, const int* __restrict__ csrc,
    int beg, int end, int g, int i, float acc[8])
{
  int e = beg;
  for (; e + 16 <= end; e += 16) {      // 16 edges in flight
    int s0 = csrc[e + g];
    int s1 = csrc[e + 4 + g];
    int s2 = csrc[e + 8 + g];
    int s3 = csrc[e + 12 + g];
    B8u w0; w0.u = *(const uint4*)(hb + (size_t)s0 * HID + i * 8);
    B8u w1; w1.u = *(const uint4*)(hb + (size_t)s1 * HID + i * 8);
    B8u w2; w2.u = *(const uint4*)(hb + (size_t)s2 * HID + i * 8);
    B8u w3; w3.u = *(const uint4*)(hb + (size_t)s3 * HID + i * 8);
#pragma unroll
    for (int j = 0; j < 8; ++j)
      acc[j] += (bf2f(w0.s[j]) + bf2f(w1.s[j])) + (bf2f(w2.s[j]) + bf2f(w3.s[j]));
  }
  int rem = end - e;                    // 0..15 -> batched predicated tail
  if (rem > 0) {
    int t0 = (g < rem)      ? csrc[e + g]      : -1;
    int t1 = (4 + g < rem)  ? csrc[e + 4 + g]  : -1;
    int t2 = (8 + g < rem)  ? csrc[e + 8 + g]  : -1;
    int t3 = (12 + g < rem) ? csrc[e + 12 + g] : -1;
    B8u r0, r1, r2, r3;
    if (t0 >= 0) r0.u = *(const uint4*)(hb + (size_t)t0 * HID + i * 8);
    if (t1 >= 0) r1.u = *(const uint4*)(hb + (size_t)t1 * HID + i * 8);
    if (t2 >= 0) r2.u = *(const uint4*)(hb + (size_t)t2 * HID + i * 8);
    if (t3 >= 0) r3.u = *(const uint4*)(hb + (size_t)t3 * HID + i * 8);
    if (t0 >= 0) {
#pragma unroll
      for (int j = 0; j < 8; ++j) acc[j] += bf2f(r0.s[j]);
    }
    if (t1 >= 0) {
#pragma unroll
      for (int j = 0; j < 8; ++j) acc[j] += bf2f(r1.s[j]);
    }
    if (t2 >= 0) {
#pragma unroll
      for (int j = 0; j < 8; ++j) acc[j] += bf2f(r2.s[j]);
    }
    if (t3 >= 0) {
#pragma unroll
      for (int j = 0; j < 8; ++j) acc[j] += bf2f(r3.s[j]);
    }
  }
}

// ---- full inline gather for one strip (prologue + rare-deg path)
static __device__ __forceinline__ void gather_strip(
    const int* __restrict__ rowptr, const int* __restrict__ csrc,
    const ushort* __restrict__ hb, const int* __restrict__ deg,
    int strip, int w, int lane, int N,
    ushort dstS[16][128], ushort dstH[16][128], int* dstDeg)
{
  int node = strip * 16 + w;
  if (node >= N) return;
  int g = lane >> 4;        // edge slot 0..3
  int i = lane & 15;        // 16B chunk of row
  if (g == 1)               // stage this node's h row (bit-identical copy)
    *(uint4*)(&dstH[w][(i ^ (w & 7)) * 8]) =
        *(const uint4*)(hb + (size_t)node * HID + i * 8);
  if (lane == 32) dstDeg[w] = deg[node];
  int beg = rowptr[node], end = rowptr[node + 1];
  float acc[8] = {0.f, 0.f, 0.f, 0.f, 0.f, 0.f, 0.f, 0.f};
  accum_range(hb, csrc, beg, end, g, i, acc);
#pragma unroll
  for (int j = 0; j < 8; ++j) {
    acc[j] += __shfl_xor(acc[j], 16, 64);
    acc[j] += __shfl_xor(acc[j], 32, 64);
  }
  if (g == 0) {
    uint4 ov;
    ov.x = ((uint)f2bf(acc[1]) << 16) | (uint)f2bf(acc[0]);
    ov.y = ((uint)f2bf(acc[3]) << 16) | (uint)f2bf(acc[2]);
    ov.z = ((uint)f2bf(acc[5]) << 16) | (uint)f2bf(acc[4]);
    ov.w = ((uint)f2bf(acc[7]) << 16) | (uint)f2bf(acc[6]);
    *(uint4*)(&dstS[w][(i ^ (w & 7)) * 8]) = ov;
  }
}

// ==== k_fused v4 (R8 + idx-state prefetch): per iteration the gather uses
// INDEX STATE (idx[7]+cnt, 8 regs) prefetched LAST iteration -> only the
// row loads' round-trip is exposed; the rowptr load for strip s+2G issues
// BEFORE the rows (in-order vmcnt: waiting on rows implies it's done) and
// the csrc refill issues after the accumulate, hidden under GEMM+epilogue.
// Paid for by moving the 9 bias scalars to an LDS table BL (net reg ~0 ->
// no spill; discriminator: VGPR stays 64, WRITE stays 25MB). deg>28 (0.2%)
// falls back to the inline loop. All accumulation orders preserved exactly
// -> bit-identical output.
__global__ __launch_bounds__(1024, 4) void k_fused(
    const int* __restrict__ rowptr, const int* __restrict__ csrc,
    const ushort* __restrict__ hbc, ushort* __restrict__ hbn,
    const ushort* __restrict__ Wcomb, const ushort* __restrict__ Whh16,
    const float* __restrict__ bvec, const float* __restrict__ b_ih,
    const float* __restrict__ b_hh, const int* __restrict__ deg, int N)
{
  __shared__ float S[6][16][132];        // 50688 B
  __shared__ ushort AT[3][2][16][128];   // 24576 B
  __shared__ int degT[3][16];            // 192 B
  __shared__ float BL[9][128];           // 4608 B bias table
  const int tid = threadIdx.x;
  const int w = tid >> 6;
  const int lane = tid & 63;
  const int quad = lane >> 4, l16 = lane & 15;   // quad = edge slot g, l16 = chunk i
  const int gm = w >> 3;            // 0: W-path (gathersum x Wcomb), 1: H-path
  const int gw = w & 7;
  const int d0 = gw * 16;

  const ushort* Wmat = gm ? Whh16 : Wcomb;
  B8u bfr[3][4];
#pragma unroll
  for (int gg = 0; gg < 3; ++gg)
#pragma unroll
    for (int kc = 0; kc < 4; ++kc) {
      int j = (d0 + gg * 128 + l16) * HID + kc * 32 + quad * 8;
      bfr[gg][kc].u = *(const uint4*)(Wmat + j);
    }

  for (int kk = tid; kk < 9 * 128; kk += 1024) {
    int grp = kk >> 7, col = kk & 127;
    const float* sp2 = (grp < 3) ? b_ih : (grp < 6 ? b_hh : bvec);
    BL[grp][col] = sp2[(grp % 3) * 128 + col];
  }

  const int ecol = tid & 127, erow0 = tid >> 7;
  const int nstrip = N >> 4;
  const int G = (int)gridDim.x;
  int s = blockIdx.x;
  if (s >= nstrip) return;

  // prologue: full inline gather for first strip; prime idx state for s+G
  gather_strip(rowptr, csrc, hbc, deg, s, w, lane, N, AT[0][0], AT[0][1], degT[0]);
  int cnt = 0; int idx[7];
#pragma unroll
  for (int j = 0; j < 7; ++j) idx[j] = 0;
  if (s + G < nstrip) {
    int node = (s + G) * 16 + w;
    int b2 = rowptr[node];
    cnt = rowptr[node + 1] - b2;
#pragma unroll
    for (int j = 0; j < 7; ++j)
      idx[j] = (4 * j + quad < cnt) ? csrc[b2 + 4 * j + quad] : 0;
  }
  asm volatile("s_waitcnt lgkmcnt(0)" ::: "memory");
  __builtin_amdgcn_sched_barrier(0);
  __builtin_amdgcn_s_barrier();

  int cur = 0;
  while (true) {
    int ns = s + G;
    bool more = ns < nstrip;
    int nxt = (cur == 2) ? 0 : cur + 1;
    if (more) {
      int node = ns * 16 + w;
      int s2 = ns + G;
      int nbeg = 0, nend = 0;
      if (s2 < nstrip) {                 // rowptr for s+2G: issue EARLY
        int node2 = s2 * 16 + w;
        nbeg = rowptr[node2];
        nend = rowptr[node2 + 1];
      }
      uint4 hrow = make_uint4(0, 0, 0, 0);
      if (quad == 1) hrow = *(const uint4*)(hbc + (size_t)node * HID + l16 * 8);
      int dgv = 0;
      if (lane == 32) dgv = deg[node];
      float acc[8] = {0.f, 0.f, 0.f, 0.f, 0.f, 0.f, 0.f, 0.f};
      if (cnt > 28) {
        // rare: full inline loop (reloads rowptr for this node)
        int beg = rowptr[node];
        accum_range(hbc, csrc, beg, beg + cnt, quad, l16, acc);
      } else {
        bool h16 = cnt >= 16;
        bool p0 = (quad < cnt), p1 = (4 + quad < cnt),
             p2 = (8 + quad < cnt), p3 = (12 + quad < cnt);
        bool p4 = (16 + quad < cnt), p5 = (20 + quad < cnt), p6 = (24 + quad < cnt);
        B8u r0, r1, r2, r3, t4, t5, t6;
        if (h16) {
          r0.u = *(const uint4*)(hbc + (size_t)idx[0] * HID + l16 * 8);
          r1.u = *(const uint4*)(hbc + (size_t)idx[1] * HID + l16 * 8);
          r2.u = *(const uint4*)(hbc + (size_t)idx[2] * HID + l16 * 8);
          r3.u = *(const uint4*)(hbc + (size_t)idx[3] * HID + l16 * 8);
        } else {
          if (p0) r0.u = *(const uint4*)(hbc + (size_t)idx[0] * HID + l16 * 8);
          if (p1) r1.u = *(const uint4*)(hbc + (size_t)idx[1] * HID + l16 * 8);
          if (p2) r2.u = *(const uint4*)(hbc + (size_t)idx[2] * HID + l16 * 8);
          if (p3) r3.u = *(const uint4*)(hbc + (size_t)idx[3] * HID + l16 * 8);
        }
        if (p4) t4.u = *(const uint4*)(hbc + (size_t)idx[4] * HID + l16 * 8);
        if (p5) t5.u = *(const uint4*)(hbc + (size_t)idx[5] * HID + l16 * 8);
        if (p6) t6.u = *(const uint4*)(hbc + (size_t)idx[6] * HID + l16 * 8);
        if (h16) {
#pragma unroll
          for (int j = 0; j < 8; ++j)
            acc[j] += (bf2f(r0.s[j]) + bf2f(r1.s[j])) + (bf2f(r2.s[j]) + bf2f(r3.s[j]));
        } else {
          if (p0) {
#pragma unroll
            for (int j = 0; j < 8; ++j) acc[j] += bf2f(r0.s[j]);
          }
          if (p1) {
#pragma unroll
            for (int j = 0; j < 8; ++j) acc[j] += bf2f(r1.s[j]);
          }
          if (p2) {
#pragma unroll
            for (int j = 0; j < 8; ++j) acc[j] += bf2f(r2.s[j]);
          }
          if (p3) {
#pragma unroll
            for (int j = 0; j < 8; ++j) acc[j] += bf2f(r3.s[j]);
          }
        }
        if (p4) {
#pragma unroll
          for (int j = 0; j < 8; ++j) acc[j] += bf2f(t4.s[j]);
        }
        if (p5) {
#pragma unroll
          for (int j = 0; j < 8; ++j) acc[j] += bf2f(t5.s[j]);
        }
        if (p6) {
#pragma unroll
          for (int j = 0; j < 8; ++j) acc[j] += bf2f(t6.s[j]);
        }
      }
#pragma unroll
      for (int j = 0; j < 8; ++j) {
        acc[j] += __shfl_xor(acc[j], 16, 64);
        acc[j] += __shfl_xor(acc[j], 32, 64);
      }
      if (quad == 0) {
        uint4 ov;
        ov.x = ((uint)f2bf(acc[1]) << 16) | (uint)f2bf(acc[0]);
        ov.y = ((uint)f2bf(acc[3]) << 16) | (uint)f2bf(acc[2]);
        ov.z = ((uint)f2bf(acc[5]) << 16) | (uint)f2bf(acc[4]);
        ov.w = ((uint)f2bf(acc[7]) << 16) | (uint)f2bf(acc[6]);
        *(uint4*)(&AT[nxt][0][w][(l16 ^ (w & 7)) * 8]) = ov;
      }
      if (quad == 1) *(uint4*)(&AT[nxt][1][w][(l16 ^ (w & 7)) * 8]) = hrow;
      if (lane == 32) degT[nxt][w] = dgv;
      // refill idx state for s+2G (rowptr already returned; csrc loads
      // complete under the GEMM+epilogue below)
      if (s2 < nstrip) {
        cnt = nend - nbeg;
#pragma unroll
        for (int j = 0; j < 7; ++j)
          idx[j] = (4 * j + quad < cnt) ? csrc[nbeg + 4 * j + quad] : 0;
      } else cnt = 0;
    }
    // GEMM + epilogue on strip s (AT[cur])
    B8u af[4];
#pragma unroll
    for (int kc = 0; kc < 4; ++kc)
      af[kc].u = *(const uint4*)(&AT[cur][gm][l16][(((quad + 4 * kc) ^ (l16 & 7)) * 8)]);
    f32x4 acc3[3] = {};
#pragma unroll
    for (int kc = 0; kc < 4; ++kc)
#pragma unroll
      for (int gg = 0; gg < 3; ++gg)
        acc3[gg] = __builtin_amdgcn_mfma_f32_16x16x32_bf16(af[kc].b, bfr[gg][kc].b, acc3[gg], 0, 0, 0);
    // (a) all waves past prev epilogue's S/AT[cur] reads -> safe to write S
    __builtin_amdgcn_s_barrier();
#pragma unroll
    for (int gg = 0; gg < 3; ++gg)
#pragma unroll
      for (int rg = 0; rg < 4; ++rg)
        S[gm * 3 + gg][quad * 4 + rg][d0 + l16] = acc3[gg][rg];
    // (b) drain own LDS ops (S writes + gather writes), leave vmcnt in flight
    asm volatile("s_waitcnt lgkmcnt(0)" ::: "memory");
    __builtin_amdgcn_sched_barrier(0);
    __builtin_amdgcn_s_barrier();
    {
      float bir = BL[0][ecol], biz = BL[1][ecol], bin_ = BL[2][ecol];
      float bhr = BL[3][ecol], bhz = BL[4][ecol], bhn = BL[5][ecol];
      float vr = BL[6][ecol], vz = BL[7][ecol], vn = BL[8][ecol];
      int n0 = s << 4;
#pragma unroll
      for (int k = 0; k < 2; ++k) {
        int row = erow0 + 8 * k;
        float dgf = (float)degT[cur][row];
        int sc = (((ecol >> 3) ^ (row & 7)) * 8) + (ecol & 7);
        float hold = bf2f(AT[cur][1][row][sc]);
        float ir  = S[0][row][ecol] + dgf * vr + bir;
        float iz  = S[1][row][ecol] + dgf * vz + biz;
        float in_ = S[2][row][ecol] + dgf * vn + bin_;
        float hr  = S[3][row][ecol] + bhr;
        float hz  = S[4][row][ecol] + bhz;
        float hn  = S[5][row][ecol] + bhn;
        float r = __builtin_amdgcn_rcpf(1.f + __expf(-(ir + hr)));
        float z = __builtin_amdgcn_rcpf(1.f + __expf(-(iz + hz)));
        float x2 = in_ + r * hn;
        float e2 = __expf(2.f * x2);
        float nv = 1.f - 2.f * __builtin_amdgcn_rcpf(e2 + 1.f);   // tanh
        float hv = (1.f - z) * nv + z * hold;
        hbn[(size_t)(n0 + row) * HID + ecol] = f2bf(hv);
      }
    }
    if (!more) break;
    s = ns; cur = nxt;
  }
}

// ---- per-graph counts from SORTED gid: binary search, no atomics
__global__ __launch_bounds__(64) void k_bounds(const int* __restrict__ gid,
                                               int* __restrict__ cnt, int N, int G) {
  int g = threadIdx.x;
  if (g >= G) return;
  int lo = 0, hi = N;
  while (lo < hi) { int mid = (lo + hi) >> 1; if (gid[mid] < g) lo = mid + 1; else hi = mid; }
  int lb0 = lo;
  lo = 0; hi = N;
  int g1 = g + 1;
  while (lo < hi) { int mid = (lo + hi) >> 1; if (gid[mid] < g1) lo = mid + 1; else hi = mid; }
  cnt[g] = lo - lb0;
}

// ---- pooling: graph_ids sorted -> run-length accumulate, few atomics
#define POOL_CHUNK 96
__global__ __launch_bounds__(128) void k_pool(const ushort* __restrict__ hb,
                                              const int* __restrict__ gid,
                                              float* __restrict__ hg, int N) {
  int d = threadIdx.x;
  int start = blockIdx.x * POOL_CHUNK;
  if (start >= N) return;
  int end = min(start + POOL_CHUNK, N);
  float acc = 0.f;
  int g = gid[start];
  for (int n = start; n < end; ++n) {
    int gn = gid[n];
    if (gn != g) { unsafeAtomicAdd(&hg[g * HID + d], acc); acc = 0.f; g = gn; }
    acc += fmaxf(bf2f(hb[(size_t)n * HID + d]), 0.f);   // relu
  }
  unsafeAtomicAdd(&hg[g * HID + d], acc);
}

__global__ __launch_bounds__(640) void k_cls(const float* __restrict__ hg,
                                             const int* __restrict__ cnt,
                                             const float* __restrict__ Wc,
                                             const float* __restrict__ bc,
                                             float* __restrict__ out, int G) {
  int t = threadIdx.x;
  if (t >= G * 10) return;
  int g = t / 10, c = t % 10;
  float inv = 1.f / fmaxf((float)cnt[g], 1.f);
  float acc = 0.f;
  for (int d = 0; d < HID; ++d) acc = fmaf(hg[g * HID + d], Wc[c * HID + d], acc);
  out[t] = acc * inv + bc[c];
}

extern "C" void kernel_launch(void* const* d_in, const int* in_sizes, int n_in,
                              void* d_out, int out_size, void* d_ws, size_t ws_size,
                              hipStream_t stream) {
  const int N = in_sizes[0];
  const int E = in_sizes[9];
  const float* m    = (const float*)d_in[0];
  const float* W_e  = (const float*)d_in[1];
  const float* b_e  = (const float*)d_in[2];
  const float* W_ih = (const float*)d_in[3];
  const float* b_ih = (const float*)d_in[4];
  const float* W_hh = (const float*)d_in[5];
  const float* b_hh = (const float*)d_in[6];
  const float* W_cls = (const float*)d_in[7];
  const float* b_cls = (const float*)d_in[8];
  const int* src = (const int*)d_in[9];
  const int* dst = (const int*)d_in[10];
  const int* gid = (const int*)d_in[11];
  const int G = out_size / 10;
  float* out = (float*)d_out;

  size_t off = 0;
  auto alloc = [&](size_t b) {
    char* p = (char*)d_ws + off;
    off += (b + 255) & ~(size_t)255;
    return (void*)p;
  };
  ushort* hb0    = (ushort*)alloc((size_t)N * HID * 2);
  ushort* hb1    = (ushort*)alloc((size_t)N * HID * 2);
  int*    deg    = (int*)   alloc((size_t)N * 4);
  int*    rowptr = (int*)   alloc((size_t)(N + 1) * 4);
  int*    csrc   = (int*)   alloc((size_t)E * 4);
  uint*   ebuf   = (uint*)  alloc((size_t)E * 4);
  int*    bhist  = (int*)   alloc((size_t)MAXBUK * 4);
  int*    bbase  = (int*)   alloc((size_t)(MAXBUK + 1) * 4);
  int*    gcur   = (int*)   alloc((size_t)MAXBUK * 4);
  ushort* Wcomb  = (ushort*)alloc((size_t)G3 * HID * 2);
  ushort* Whh16  = (ushort*)alloc((size_t)G3 * HID * 2);
  float*  bvec   = (float*) alloc((size_t)G3 * 4);
  float*  hg     = (float*) alloc((size_t)G * HID * 4);
  int*    cnt    = (int*)   alloc((size_t)G * 4);
  ushort* m16    = (ushort*)alloc((size_t)N * 2);
  ushort* hsum0  = (ushort*)alloc((size_t)N * 2);
  ushort* Wc0    = (ushort*)alloc((size_t)G3 * 2);
  ushort* Wh0    = (ushort*)alloc((size_t)G3 * 2);
  if (off > ws_size) return;   // workspace too small -> visible failure

  const int NBUK = (N + BNODES - 1) >> BSHIFT;   // 196 at N=100k (<= MAXBUK)

  k_weights<<<2 * G3, HID, 0, stream>>>(W_e, b_e, W_ih, W_hh, Wcomb, Whh16, bvec, Wc0, Wh0);
  k_minit<<<(N + 255) / 256, 256, 0, stream>>>(m, m16, N);
  hipMemsetAsync(bhist, 0, (size_t)MAXBUK * 4, stream);
  k_bh<<<256, 256, 0, stream>>>(dst, bhist, E);
  k_bsc<<<1, MAXBUK, 0, stream>>>(bhist, bbase, gcur, rowptr, E, N);
  k_part<<<(E + PART_EPB - 1) / PART_EPB, 256, 0, stream>>>(src, dst, gcur, ebuf, E);
  k_fill2<<<NBUK, 256, 0, stream>>>(ebuf, bbase, csrc, rowptr, deg, N);

  // ---- step 0: h = [m,0,...,0] is rank-1 -> scalar gather + rank-1 GRU
  k_gather0<<<(N + 255) / 256, 256, 0, stream>>>(rowptr, csrc, m16, hsum0, N);
  k_gru0<<<(N * HID + 255) / 256, 256, 0, stream>>>(hsum0, m16, deg, Wc0, Wh0,
                                                    bvec, b_ih, b_hh, hb1, N);

  ushort* hbc = hb1;
  ushort* hbn = hb0;
  const int nstrip = N >> 4;
  const int fuse_blocks = nstrip < 256 ? nstrip : 256;   // 1 block/CU
  for (int s = 1; s < TSTEPS; ++s) {
    k_fused<<<fuse_blocks, 1024, 0, stream>>>(rowptr, csrc, hbc, hbn,
                                              Wcomb, Whh16, bvec, b_ih, b_hh, deg, N);
    ushort* t = hbc; hbc = hbn; hbn = t;
  }

  hipMemsetAsync(hg, 0, (size_t)G * HID * 4, stream);
  k_bounds<<<1, 64, 0, stream>>>(gid, cnt, N, G);
  k_pool<<<(N + POOL_CHUNK - 1) / POOL_CHUNK, HID, 0, stream>>>(hbc, gid, hg, N);
  k_cls<<<1, 640, 0, stream>>>(hg, cnt, W_cls, b_cls, out, G);
}

// Round 11
// 1025.455 us; speedup vs baseline: 1.2688x; 1.2688x over previous
//
#include <hip/hip_runtime.h>

#define HID 128
#define G3  384   // 3*HID
#define TSTEPS 5
#define BSHIFT 9          // 512 nodes per bucket
#define BNODES (1 << BSHIFT)
#define MAXBUK 256        // supports N up to 128k
#define PART_EPB 8192     // edges per k_part block
#define DBUK 64           // degree-sort buckets

typedef unsigned int  uint;
typedef unsigned short ushort;

typedef float  f32x4  __attribute__((ext_vector_type(4)));
typedef __bf16 bf16x8 __attribute__((ext_vector_type(8)));

union B8u { uint4 u; bf16x8 b; ushort s[8]; };

static __device__ inline ushort f2bf(float f) {
  uint u = __float_as_uint(f);
  uint r = u + 0x7fffu + ((u >> 16) & 1u);   // RTN-even
  return (ushort)(r >> 16);
}
static __device__ inline float bf2f(ushort s) {
  return __uint_as_float(((uint)s) << 16);
}

// ---- once per call: W_comb = W_ih @ W_e (bf16), bvec = W_ih @ b_e, W_hh -> bf16
__global__ __launch_bounds__(128) void k_weights(
    const float* __restrict__ W_e, const float* __restrict__ b_e,
    const float* __restrict__ W_ih, const float* __restrict__ W_hh,
    ushort* __restrict__ Wcomb, ushort* __restrict__ Whh16, float* __restrict__ bvec,
    ushort* __restrict__ Wc0, ushort* __restrict__ Wh0)
{
  int j = blockIdx.x, t = threadIdx.x;
  if (j < G3) {
    __shared__ float row[HID];
    row[t] = W_ih[j * HID + t];
    __syncthreads();
    float acc = 0.f;
    for (int k = 0; k < HID; ++k) acc = fmaf(row[k], W_e[k * HID + t], acc);
    Wcomb[j * HID + t] = f2bf(acc);
    if (t == 0) {
      Wc0[j] = f2bf(acc);
      float b = 0.f;
      for (int k = 0; k < HID; ++k) b += row[k] * b_e[k];
      bvec[j] = b;
    }
  } else {
    int j2 = j - G3;
    Whh16[j2 * HID + t] = f2bf(W_hh[j2 * HID + t]);
    if (t == 0) Wh0[j2] = f2bf(W_hh[j2 * HID]);
  }
}

// ---- CSR build, stage 1: bucket histogram of dst (LDS-aggregated)
__global__ __launch_bounds__(256) void k_bh(const int* __restrict__ dst,
                                            int* __restrict__ bhist, int E) {
  __shared__ int lh[MAXBUK];
  int t = threadIdx.x;
  if (t < MAXBUK) lh[t] = 0;
  __syncthreads();
  for (int e = blockIdx.x * 256 + t; e < E; e += gridDim.x * 256)
    atomicAdd(&lh[dst[e] >> BSHIFT], 1);
  __syncthreads();
  if (t < MAXBUK && lh[t]) atomicAdd(&bhist[t], lh[t]);
}

// ---- stage 2: serial scan of <=256 bucket counts (trivial size)
__global__ __launch_bounds__(256) void k_bsc(const int* __restrict__ bhist,
                                             int* __restrict__ bbase,
                                             int* __restrict__ gcur,
                                             int* __restrict__ rowptr, int E, int N) {
  __shared__ int ls[MAXBUK];
  int t = threadIdx.x;
  ls[t] = bhist[t];
  __syncthreads();
  if (t == 0) {
    int run = 0;
    for (int i = 0; i < MAXBUK; ++i) {
      bbase[i] = run; gcur[i] = run; run += ls[i];
    }
    bbase[MAXBUK] = run;
    rowptr[N] = E;
  }
}

// ---- stage 3: partition packed (dl<<20)|src into bucket-grouped ebuf.
__global__ __launch_bounds__(256) void k_part(
    const int* __restrict__ src, const int* __restrict__ dst,
    int* __restrict__ gcur, uint* __restrict__ ebuf, int E) {
  __shared__ int lh[MAXBUK], lbase[MAXBUK], lcur[MAXBUK];
  int t = threadIdx.x;
  int base = blockIdx.x * PART_EPB;
  if (t < MAXBUK) lh[t] = 0;
  __syncthreads();
#pragma unroll 4
  for (int j = 0; j < PART_EPB / 256; ++j) {
    int e = base + j * 256 + t;
    if (e < E) atomicAdd(&lh[dst[e] >> BSHIFT], 1);
  }
  __syncthreads();
  if (t < MAXBUK) {
    lbase[t] = lh[t] ? atomicAdd(&gcur[t], lh[t]) : 0;
    lcur[t] = 0;
  }
  __syncthreads();
#pragma unroll 4
  for (int j = 0; j < PART_EPB / 256; ++j) {
    int e = base + j * 256 + t;
    if (e < E) {
      int d = dst[e];
      int b = d >> BSHIFT;
      int p = atomicAdd(&lcur[b], 1);
      ebuf[lbase[b] + p] = (uint)src[e] | ((uint)(d & (BNODES - 1)) << 20);
    }
  }
}

// ---- stage 4: one block per bucket: LDS hist -> scan -> rowptr/deg -> scatter
__global__ __launch_bounds__(256) void k_fill2(
    const uint* __restrict__ ebuf, const int* __restrict__ bbase,
    int* __restrict__ csrc, int* __restrict__ rowptr, int* __restrict__ deg, int N) {
  __shared__ int hcnt[BNODES];
  __shared__ int wls[4];
  int t = threadIdx.x;
  int b = blockIdx.x;
  int ebeg = bbase[b], eend = bbase[b + 1];
  for (int i = t; i < BNODES; i += 256) hcnt[i] = 0;
  __syncthreads();
  for (int e = ebeg + t; e < eend; e += 256)
    atomicAdd(&hcnt[ebuf[e] >> 20], 1);
  __syncthreads();
  const int PER = BNODES / 256;
  int lane = t & 63, wv = t >> 6;
  int x[PER]; int s = 0;
#pragma unroll
  for (int i = 0; i < PER; ++i) { x[i] = hcnt[PER * t + i]; s += x[i]; }
  int incl = s;
#pragma unroll
  for (int off = 1; off < 64; off <<= 1) {
    int u = __shfl_up(incl, off, 64);
    if (lane >= off) incl += u;
  }
  if (lane == 63) wls[wv] = incl;
  __syncthreads();
  int wbase = 0;
  for (int i = 0; i < wv; ++i) wbase += wls[i];
  int run = wbase + incl - s;
#pragma unroll
  for (int i = 0; i < PER; ++i) {
    int node = (b << BSHIFT) + PER * t + i;
    hcnt[PER * t + i] = run;
    if (node < N) { rowptr[node] = ebeg + run; deg[node] = x[i]; }
    run += x[i];
  }
  __syncthreads();
  for (int e = ebeg + t; e < eend; e += 256) {
    uint v = ebuf[e];
    int p = atomicAdd(&hcnt[v >> 20], 1);
    csrc[ebeg + p] = (int)(v & 0xFFFFFu);
  }
}

// ---- degree-sort: histogram -> scan -> scatter. Produces sorted-slot views
// (orig2 = slot->node, beg2/deg2s = slot's CSR range). Within-bucket order is
// atomic-arbitrary; per-node computation is order-independent -> output
// bit-identical.
__global__ __launch_bounds__(256) void k_dhist(const int* __restrict__ deg,
                                               int* __restrict__ dhist, int N) {
  __shared__ int lh[DBUK];
  int t = threadIdx.x;
  if (t < DBUK) lh[t] = 0;
  __syncthreads();
  for (int v = blockIdx.x * 256 + t; v < N; v += gridDim.x * 256)
    atomicAdd(&lh[min(deg[v], DBUK - 1)], 1);
  __syncthreads();
  if (t < DBUK && lh[t]) atomicAdd(&dhist[t], lh[t]);
}

__global__ __launch_bounds__(64) void k_dscan(const int* __restrict__ dhist,
                                              int* __restrict__ dcur) {
  if (threadIdx.x == 0) {
    int run = 0;
    for (int i = 0; i < DBUK; ++i) { dcur[i] = run; run += dhist[i]; }
  }
}

__global__ __launch_bounds__(256) void k_dscatter(
    const int* __restrict__ deg, const int* __restrict__ rowptr,
    int* __restrict__ dcur, int* __restrict__ orig2,
    int* __restrict__ beg2, int* __restrict__ deg2s, int N) {
  int v = blockIdx.x * 256 + threadIdx.x;
  if (v >= N) return;
  int d = deg[v];
  int k = atomicAdd(&dcur[min(d, DBUK - 1)], 1);
  orig2[k] = v;
  beg2[k] = rowptr[v];
  deg2s[k] = d;
}

// ---- m16[v] = bf16(m[v]) — the only nonzero column of h at t=0
__global__ void k_minit(const float* __restrict__ m, ushort* __restrict__ m16, int N) {
  int v = blockIdx.x * 256 + threadIdx.x;
  if (v < N) m16[v] = f2bf(m[v]);
}

// ---- step-0 gather: h rows are [m,0,...,0] so only dim 0 needs summing.
__global__ __launch_bounds__(256) void k_gather0(
    const int* __restrict__ rowptr, const int* __restrict__ csrc,
    const ushort* __restrict__ m16, ushort* __restrict__ hsum0, int N)
{
  int v = blockIdx.x * 256 + threadIdx.x;
  if (v >= N) return;
  int beg = rowptr[v], end = rowptr[v + 1];
  float a0 = 0.f, a1 = 0.f, a2 = 0.f, a3 = 0.f;
  int e = beg;
  for (; e + 16 <= end; e += 16) {
    a0 += (bf2f(m16[csrc[e + 0]]) + bf2f(m16[csrc[e + 4]])) +
          (bf2f(m16[csrc[e + 8]]) + bf2f(m16[csrc[e + 12]]));
    a1 += (bf2f(m16[csrc[e + 1]]) + bf2f(m16[csrc[e + 5]])) +
          (bf2f(m16[csrc[e + 9]]) + bf2f(m16[csrc[e + 13]]));
    a2 += (bf2f(m16[csrc[e + 2]]) + bf2f(m16[csrc[e + 6]])) +
          (bf2f(m16[csrc[e + 10]]) + bf2f(m16[csrc[e + 14]]));
    a3 += (bf2f(m16[csrc[e + 3]]) + bf2f(m16[csrc[e + 7]])) +
          (bf2f(m16[csrc[e + 11]]) + bf2f(m16[csrc[e + 15]]));
  }
  for (; e < end; e += 4) {
    if (e + 0 < end) a0 += bf2f(m16[csrc[e + 0]]);
    if (e + 1 < end) a1 += bf2f(m16[csrc[e + 1]]);
    if (e + 2 < end) a2 += bf2f(m16[csrc[e + 2]]);
    if (e + 3 < end) a3 += bf2f(m16[csrc[e + 3]]);
  }
  hsum0[v] = f2bf((a0 + a1) + (a2 + a3));
}

// ---- step-0 GRU: both GEMMs are rank-1 (only k=0 of A/H nonzero).
__global__ __launch_bounds__(256) void k_gru0(
    const ushort* __restrict__ hsum0, const ushort* __restrict__ m16,
    const int* __restrict__ deg,
    const ushort* __restrict__ Wc0, const ushort* __restrict__ Wh0,
    const float* __restrict__ bvec, const float* __restrict__ b_ih,
    const float* __restrict__ b_hh, ushort* __restrict__ hbn, int N)
{
  int idx = blockIdx.x * 256 + threadIdx.x;
  if (idx >= N * HID) return;
  int n = idx >> 7, d = idx & (HID - 1);
  float s0 = bf2f(hsum0[n]);
  float h0 = bf2f(m16[n]);
  float degf = (float)deg[n];
  float acc0 = s0 * bf2f(Wc0[d]);
  float acc1 = s0 * bf2f(Wc0[d + 128]);
  float acc2 = s0 * bf2f(Wc0[d + 256]);
  float acc3 = h0 * bf2f(Wh0[d]);
  float acc4 = h0 * bf2f(Wh0[d + 128]);
  float acc5 = h0 * bf2f(Wh0[d + 256]);
  float hold = (d == 0) ? h0 : 0.f;
  float ir = acc0 + degf * bvec[d] + b_ih[d];
  float iz = acc1 + degf * bvec[d + 128] + b_ih[d + 128];
  float in_ = acc2 + degf * bvec[d + 256] + b_ih[d + 256];
  float hr = acc3 + b_hh[d];
  float hz = acc4 + b_hh[d + 128];
  float hn = acc5 + b_hh[d + 256];
  float r = __builtin_amdgcn_rcpf(1.f + __expf(-(ir + hr)));
  float z = __builtin_amdgcn_rcpf(1.f + __expf(-(iz + hz)));
  float x2 = in_ + r * hn;
  float e2 = __expf(2.f * x2);
  float nv = 1.f - 2.f * __builtin_amdgcn_rcpf(e2 + 1.f);   // tanh
  float hv = (1.f - z) * nv + z * hold;
  hbn[idx] = f2bf(hv);
}

// ---- shared accumulate core (R8 semantics: 16-chunks tree + batched tail)
static __device__ __forceinline__ void accum_range(
    const ushort* __restrict__ hb, const int* __restrict__ csrc,
    int beg, int end, int g, int i, float acc[8])
{
  int e = beg;
  for (; e + 16 <= end; e += 16) {      // 16 edges in flight
    int s0 = csrc[e + g];
    int s1 = csrc[e + 4 + g];
    int s2 = csrc[e + 8 + g];
    int s3 = csrc[e + 12 + g];
    B8u w0; w0.u = *(const uint4*)(hb + (size_t)s0 * HID + i * 8);
    B8u w1; w1.u = *(const uint4*)(hb + (size_t)s1 * HID + i * 8);
    B8u w2; w2.u = *(const uint4*)(hb + (size_t)s2 * HID + i * 8);
    B8u w3; w3.u = *(const uint4*)(hb + (size_t)s3 * HID + i * 8);
#pragma unroll
    for (int j = 0; j < 8; ++j)
      acc[j] += (bf2f(w0.s[j]) + bf2f(w1.s[j])) + (bf2f(w2.s[j]) + bf2f(w3.s[j]));
  }
  int rem = end - e;                    // 0..15 -> batched predicated tail
  if (rem > 0) {
    int t0 = (g < rem)      ? csrc[e + g]      : -1;
    int t1 = (4 + g < rem)  ? csrc[e + 4 + g]  : -1;
    int t2 = (8 + g < rem)  ? csrc[e + 8 + g]  : -1;
    int t3 = (12 + g < rem) ? csrc[e + 12 + g] : -1;
    B8u r0, r1, r2, r3;
    if (t0 >= 0) r0.u = *(const uint4*)(hb + (size_t)t0 * HID + i * 8);
    if (t1 >= 0) r1.u = *(const uint4*)(hb + (size_t)t1 * HID + i * 8);
    if (t2 >= 0) r2.u = *(const uint4*)(hb + (size_t)t2 * HID + i * 8);
    if (t3 >= 0) r3.u = *(const uint4*)(hb + (size_t)t3 * HID + i * 8);
    if (t0 >= 0) {
#pragma unroll
      for (int j = 0; j < 8; ++j) acc[j] += bf2f(r0.s[j]);
    }
    if (t1 >= 0) {
#pragma unroll
      for (int j = 0; j < 8; ++j) acc[j] += bf2f(r1.s[j]);
    }
    if (t2 >= 0) {
#pragma unroll
      for (int j = 0; j < 8; ++j) acc[j] += bf2f(r2.s[j]);
    }
    if (t3 >= 0) {
#pragma unroll
      for (int j = 0; j < 8; ++j) acc[j] += bf2f(r3.s[j]);
    }
  }
}

// ---- gather one SORTED strip: slot k = strip*16 + w; meta loads (orig2/
// beg2/deg2s) are coalesced and parallel (1 RT), then csrc || hrow (1 RT),
// then rows (1 RT) — same 3-RT depth as R8, but all 16 waves now have
// near-identical degree -> no barrier straggler.
static __device__ __forceinline__ void gather_strip_sorted(
    const int* __restrict__ beg2, const int* __restrict__ deg2s,
    const int* __restrict__ orig2, const int* __restrict__ csrc,
    const ushort* __restrict__ hb,
    int strip, int w, int lane, int N,
    ushort dstS[16][128], ushort dstH[16][128], int* dstDeg, int* dstOrig)
{
  int k = strip * 16 + w;
  if (k >= N) return;
  int g = lane >> 4;        // edge slot 0..3
  int i = lane & 15;        // 16B chunk of row
  int orig = orig2[k];
  int beg = beg2[k];
  int cnt = deg2s[k];
  if (g == 1)               // stage this node's h row (bit-identical copy)
    *(uint4*)(&dstH[w][(i ^ (w & 7)) * 8]) =
        *(const uint4*)(hb + (size_t)orig * HID + i * 8);
  if (lane == 0) dstOrig[w] = orig;
  if (lane == 32) dstDeg[w] = cnt;      // deg[v] == CSR row length
  float acc[8] = {0.f, 0.f, 0.f, 0.f, 0.f, 0.f, 0.f, 0.f};
  accum_range(hb, csrc, beg, beg + cnt, g, i, acc);
#pragma unroll
  for (int j = 0; j < 8; ++j) {
    acc[j] += __shfl_xor(acc[j], 16, 64);
    acc[j] += __shfl_xor(acc[j], 32, 64);
  }
  if (g == 0) {
    uint4 ov;
    ov.x = ((uint)f2bf(acc[1]) << 16) | (uint)f2bf(acc[0]);
    ov.y = ((uint)f2bf(acc[3]) << 16) | (uint)f2bf(acc[2]);
    ov.z = ((uint)f2bf(acc[5]) << 16) | (uint)f2bf(acc[4]);
    ov.w = ((uint)f2bf(acc[7]) << 16) | (uint)f2bf(acc[6]);
    *(uint4*)(&dstS[w][(i ^ (w & 7)) * 8]) = ov;
  }
}

// ==== k_fused (R8 structure + degree-sorted strips): gather + dual-GEMM +
// GRU per sorted strip. All 16 waves of a strip have near-equal degree
// (counting sort) -> the per-strip barrier no longer locks to a Poisson-max
// straggler. Per-node math identical to R8 (CSR order, MFMA order, epilogue
// exprs); epilogue writes hbn[orig] -> bit-identical output. Register delta
// vs R8 ~ +1 (orig, short-lived) -> no spill expected (discriminator:
// WRITE_SIZE stays ~25MB).
__global__ __launch_bounds__(1024, 4) void k_fused(
    const int* __restrict__ beg2, const int* __restrict__ deg2s,
    const int* __restrict__ orig2, const int* __restrict__ csrc,
    const ushort* __restrict__ hbc, ushort* __restrict__ hbn,
    const ushort* __restrict__ Wcomb, const ushort* __restrict__ Whh16,
    const float* __restrict__ bvec, const float* __restrict__ b_ih,
    const float* __restrict__ b_hh, int N)
{
  __shared__ float S[6][16][132];        // 50688 B, +4 pad
  __shared__ ushort AT[3][2][16][128];   // 24576 B: [parity][0=gathersum,1=hrow]
  __shared__ int degT[3][16];
  __shared__ int origT[3][16];
  const int tid = threadIdx.x;
  const int w = tid >> 6;
  const int lane = tid & 63;
  const int quad = lane >> 4, l16 = lane & 15;
  const int gm = w >> 3;            // 0: W-path (gathersum x Wcomb), 1: H-path
  const int gw = w & 7;
  const int d0 = gw * 16;

  const ushort* Wmat = gm ? Whh16 : Wcomb;
  B8u bfr[3][4];
#pragma unroll
  for (int g = 0; g < 3; ++g)
#pragma unroll
    for (int kc = 0; kc < 4; ++kc) {
      int j = (d0 + g * 128 + l16) * HID + kc * 32 + quad * 8;
      bfr[g][kc].u = *(const uint4*)(Wmat + j);
    }

  const int ecol = tid & 127, erow0 = tid >> 7;
  const float bir = b_ih[ecol], biz = b_ih[ecol + 128], bin_ = b_ih[ecol + 256];
  const float bhr = b_hh[ecol], bhz = b_hh[ecol + 128], bhn = b_hh[ecol + 256];
  const float vr = bvec[ecol], vz = bvec[ecol + 128], vn = bvec[ecol + 256];

  const int nstrip = N >> 4;
  const int G = (int)gridDim.x;
  int s = blockIdx.x;
  if (s >= nstrip) return;

  gather_strip_sorted(beg2, deg2s, orig2, csrc, hbc, s, w, lane, N,
                      AT[0][0], AT[0][1], degT[0], origT[0]);
  asm volatile("s_waitcnt lgkmcnt(0)" ::: "memory");
  __builtin_amdgcn_sched_barrier(0);
  __builtin_amdgcn_s_barrier();

  int cur = 0;
  while (true) {
    int ns = s + G;
    bool more = ns < nstrip;
    int nxt = (cur == 2) ? 0 : cur + 1;
    if (more)   // prefetch-gather next strip; writes only parity 'nxt'
      gather_strip_sorted(beg2, deg2s, orig2, csrc, hbc, ns, w, lane, N,
                          AT[nxt][0], AT[nxt][1], degT[nxt], origT[nxt]);
    // A-fragments from LDS (chunk-swizzled; <=2-way bank alias = free)
    B8u af[4];
#pragma unroll
    for (int kc = 0; kc < 4; ++kc)
      af[kc].u = *(const uint4*)(&AT[cur][gm][l16][(((quad + 4 * kc) ^ (l16 & 7)) * 8)]);
    f32x4 acc[3] = {};
#pragma unroll
    for (int kc = 0; kc < 4; ++kc)
#pragma unroll
      for (int g = 0; g < 3; ++g)
        acc[g] = __builtin_amdgcn_mfma_f32_16x16x32_bf16(af[kc].b, bfr[g][kc].b, acc[g], 0, 0, 0);
    // (a) all waves past prev epilogue's S/AT[cur] reads -> safe to write S
    __builtin_amdgcn_s_barrier();
#pragma unroll
    for (int g = 0; g < 3; ++g)
#pragma unroll
      for (int rg = 0; rg < 4; ++rg)
        S[gm * 3 + g][quad * 4 + rg][d0 + l16] = acc[g][rg];
    // (b) drain own LDS ops (S writes + gather writes), leave vmcnt in flight
    asm volatile("s_waitcnt lgkmcnt(0)" ::: "memory");
    __builtin_amdgcn_sched_barrier(0);
    __builtin_amdgcn_s_barrier();
    int n0 = s << 4;
#pragma unroll
    for (int k = 0; k < 2; ++k) {
      int row = erow0 + 8 * k;
      float dgf = (float)degT[cur][row];
      int og = origT[cur][row];
      int sc = (((ecol >> 3) ^ (row & 7)) * 8) + (ecol & 7);
      float hold = bf2f(AT[cur][1][row][sc]);
      float ir  = S[0][row][ecol] + dgf * vr + bir;
      float iz  = S[1][row][ecol] + dgf * vz + biz;
      float in_ = S[2][row][ecol] + dgf * vn + bin_;
      float hr  = S[3][row][ecol] + bhr;
      float hz  = S[4][row][ecol] + bhz;
      float hn  = S[5][row][ecol] + bhn;
      float r = __builtin_amdgcn_rcpf(1.f + __expf(-(ir + hr)));
      float z = __builtin_amdgcn_rcpf(1.f + __expf(-(iz + hz)));
      float x2 = in_ + r * hn;
      float e2 = __expf(2.f * x2);
      float nv = 1.f - 2.f * __builtin_amdgcn_rcpf(e2 + 1.f);   // tanh
      float hv = (1.f - z) * nv + z * hold;
      if (n0 + row < N)
        hbn[(size_t)og * HID + ecol] = f2bf(hv);
    }
    if (!more) break;
    s = ns; cur = nxt;
  }
}

// ---- per-graph counts from SORTED gid: binary search, no atomics
__global__ __launch_bounds__(64) void k_bounds(const int* __restrict__ gid,
                                               int* __restrict__ cnt, int N, int G) {
  int g = threadIdx.x;
  if (g >= G) return;
  int lo = 0, hi = N;
  while (lo < hi) { int mid = (lo + hi) >> 1; if (gid[mid] < g) lo = mid + 1; else hi = mid; }
  int lb0 = lo;
  lo = 0; hi = N;
  int g1 = g + 1;
  while (lo < hi) { int mid = (lo + hi) >> 1; if (gid[mid] < g1) lo = mid + 1; else hi = mid; }
  cnt[g] = lo - lb0;
}

// ---- pooling: graph_ids sorted -> run-length accumulate, few atomics
#define POOL_CHUNK 96
__global__ __launch_bounds__(128) void k_pool(const ushort* __restrict__ hb,
                                              const int* __restrict__ gid,
                                              float* __restrict__ hg, int N) {
  int d = threadIdx.x;
  int start = blockIdx.x * POOL_CHUNK;
  if (start >= N) return;
  int end = min(start + POOL_CHUNK, N);
  float acc = 0.f;
  int g = gid[start];
  for (int n = start; n < end; ++n) {
    int gn = gid[n];
    if (gn != g) { unsafeAtomicAdd(&hg[g * HID + d], acc); acc = 0.f; g = gn; }
    acc += fmaxf(bf2f(hb[(size_t)n * HID + d]), 0.f);   // relu
  }
  unsafeAtomicAdd(&hg[g * HID + d], acc);
}

__global__ __launch_bounds__(640) void k_cls(const float* __restrict__ hg,
                                             const int* __restrict__ cnt,
                                             const float* __restrict__ Wc,
                                             const float* __restrict__ bc,
                                             float* __restrict__ out, int G) {
  int t = threadIdx.x;
  if (t >= G * 10) return;
  int g = t / 10, c = t % 10;
  float inv = 1.f / fmaxf((float)cnt[g], 1.f);
  float acc = 0.f;
  for (int d = 0; d < HID; ++d) acc = fmaf(hg[g * HID + d], Wc[c * HID + d], acc);
  out[t] = acc * inv + bc[c];
}

extern "C" void kernel_launch(void* const* d_in, const int* in_sizes, int n_in,
                              void* d_out, int out_size, void* d_ws, size_t ws_size,
                              hipStream_t stream) {
  const int N = in_sizes[0];
  const int E = in_sizes[9];
  const float* m    = (const float*)d_in[0];
  const float* W_e  = (const float*)d_in[1];
  const float* b_e  = (const float*)d_in[2];
  const float* W_ih = (const float*)d_in[3];
  const float* b_ih = (const float*)d_in[4];
  const float* W_hh = (const float*)d_in[5];
  const float* b_hh = (const float*)d_in[6];
  const float* W_cls = (const float*)d_in[7];
  const float* b_cls = (const float*)d_in[8];
  const int* src = (const int*)d_in[9];
  const int* dst = (const int*)d_in[10];
  const int* gid = (const int*)d_in[11];
  const int G = out_size / 10;
  float* out = (float*)d_out;

  size_t off = 0;
  auto alloc = [&](size_t b) {
    char* p = (char*)d_ws + off;
    off += (b + 255) & ~(size_t)255;
    return (void*)p;
  };
  ushort* hb0    = (ushort*)alloc((size_t)N * HID * 2);
  ushort* hb1    = (ushort*)alloc((size_t)N * HID * 2);
  int*    deg    = (int*)   alloc((size_t)N * 4);
  int*    rowptr = (int*)   alloc((size_t)(N + 1) * 4);
  int*    csrc   = (int*)   alloc((size_t)E * 4);
  uint*   ebuf   = (uint*)  alloc((size_t)E * 4);
  int*    bhist  = (int*)   alloc((size_t)MAXBUK * 4);
  int*    bbase  = (int*)   alloc((size_t)(MAXBUK + 1) * 4);
  int*    gcur   = (int*)   alloc((size_t)MAXBUK * 4);
  ushort* Wcomb  = (ushort*)alloc((size_t)G3 * HID * 2);
  ushort* Whh16  = (ushort*)alloc((size_t)G3 * HID * 2);
  float*  bvec   = (float*) alloc((size_t)G3 * 4);
  float*  hg     = (float*) alloc((size_t)G * HID * 4);
  int*    cnt    = (int*)   alloc((size_t)G * 4);
  ushort* m16    = (ushort*)alloc((size_t)N * 2);
  ushort* hsum0  = (ushort*)alloc((size_t)N * 2);
  ushort* Wc0    = (ushort*)alloc((size_t)G3 * 2);
  ushort* Wh0    = (ushort*)alloc((size_t)G3 * 2);
  int*    dhist  = (int*)   alloc((size_t)DBUK * 4);
  int*    dcur   = (int*)   alloc((size_t)DBUK * 4);
  int*    orig2  = (int*)   alloc((size_t)N * 4);
  int*    beg2   = (int*)   alloc((size_t)N * 4);
  int*    deg2s  = (int*)   alloc((size_t)N * 4);
  if (off > ws_size) return;   // workspace too small -> visible failure

  const int NBUK = (N + BNODES - 1) >> BSHIFT;   // 196 at N=100k (<= MAXBUK)

  k_weights<<<2 * G3, HID, 0, stream>>>(W_e, b_e, W_ih, W_hh, Wcomb, Whh16, bvec, Wc0, Wh0);
  k_minit<<<(N + 255) / 256, 256, 0, stream>>>(m, m16, N);
  hipMemsetAsync(bhist, 0, (size_t)MAXBUK * 4, stream);
  k_bh<<<256, 256, 0, stream>>>(dst, bhist, E);
  k_bsc<<<1, MAXBUK, 0, stream>>>(bhist, bbase, gcur, rowptr, E, N);
  k_part<<<(E + PART_EPB - 1) / PART_EPB, 256, 0, stream>>>(src, dst, gcur, ebuf, E);
  k_fill2<<<NBUK, 256, 0, stream>>>(ebuf, bbase, csrc, rowptr, deg, N);

  // ---- degree-sort the node processing order (one-time, ~20us)
  hipMemsetAsync(dhist, 0, (size_t)DBUK * 4, stream);
  k_dhist<<<64, 256, 0, stream>>>(deg, dhist, N);
  k_dscan<<<1, 64, 0, stream>>>(dhist, dcur);
  k_dscatter<<<(N + 255) / 256, 256, 0, stream>>>(deg, rowptr, dcur, orig2, beg2, deg2s, N);

  // ---- step 0: h = [m,0,...,0] is rank-1 -> scalar gather + rank-1 GRU
  k_gather0<<<(N + 255) / 256, 256, 0, stream>>>(rowptr, csrc, m16, hsum0, N);
  k_gru0<<<(N * HID + 255) / 256, 256, 0, stream>>>(hsum0, m16, deg, Wc0, Wh0,
                                                    bvec, b_ih, b_hh, hb1, N);

  ushort* hbc = hb1;
  ushort* hbn = hb0;
  const int nstrip = N >> 4;
  const int fuse_blocks = nstrip < 256 ? nstrip : 256;   // 1 block/CU (R8 best)
  for (int s = 1; s < TSTEPS; ++s) {
    k_fused<<<fuse_blocks, 1024, 0, stream>>>(beg2, deg2s, orig2, csrc, hbc, hbn,
                                              Wcomb, Whh16, bvec, b_ih, b_hh, N);
    ushort* t = hbc; hbc = hbn; hbn = t;
  }

  hipMemsetAsync(hg, 0, (size_t)G * HID * 4, stream);
  k_bounds<<<1, 64, 0, stream>>>(gid, cnt, N, G);
  k_pool<<<(N + POOL_CHUNK - 1) / POOL_CHUNK, HID, 0, stream>>>(hbc, gid, hg, N);
  k_cls<<<1, 640, 0, stream>>>(hg, cnt, W_cls, b_cls, out, G);
}

// Round 12
// 752.920 us; speedup vs baseline: 1.7281x; 1.3620x over previous
//
#include <hip/hip_runtime.h>

#define HID 128
#define G3  384   // 3*HID
#define TSTEPS 5
#define BSHIFT 9          // 512 nodes per bucket
#define BNODES (1 << BSHIFT)
#define MAXBUK 256        // supports N up to 128k
#define PART_EPB 8192     // edges per k_part block
#define DBUK 64           // degree-sort buckets

typedef unsigned int  uint;
typedef unsigned short ushort;

typedef float  f32x4  __attribute__((ext_vector_type(4)));
typedef __bf16 bf16x8 __attribute__((ext_vector_type(8)));

union B8u { uint4 u; bf16x8 b; ushort s[8]; };

static __device__ inline ushort f2bf(float f) {
  uint u = __float_as_uint(f);
  uint r = u + 0x7fffu + ((u >> 16) & 1u);   // RTN-even
  return (ushort)(r >> 16);
}
static __device__ inline float bf2f(ushort s) {
  return __uint_as_float(((uint)s) << 16);
}

// ---- once per call: W_comb = W_ih @ W_e (bf16), bvec = W_ih @ b_e, W_hh -> bf16
__global__ __launch_bounds__(128) void k_weights(
    const float* __restrict__ W_e, const float* __restrict__ b_e,
    const float* __restrict__ W_ih, const float* __restrict__ W_hh,
    ushort* __restrict__ Wcomb, ushort* __restrict__ Whh16, float* __restrict__ bvec,
    ushort* __restrict__ Wc0, ushort* __restrict__ Wh0)
{
  int j = blockIdx.x, t = threadIdx.x;
  if (j < G3) {
    __shared__ float row[HID];
    row[t] = W_ih[j * HID + t];
    __syncthreads();
    float acc = 0.f;
    for (int k = 0; k < HID; ++k) acc = fmaf(row[k], W_e[k * HID + t], acc);
    Wcomb[j * HID + t] = f2bf(acc);
    if (t == 0) {
      Wc0[j] = f2bf(acc);
      float b = 0.f;
      for (int k = 0; k < HID; ++k) b += row[k] * b_e[k];
      bvec[j] = b;
    }
  } else {
    int j2 = j - G3;
    Whh16[j2 * HID + t] = f2bf(W_hh[j2 * HID + t]);
    if (t == 0) Wh0[j2] = f2bf(W_hh[j2 * HID]);
  }
}

// ---- CSR build, stage 1: bucket histogram of dst (LDS-aggregated)
__global__ __launch_bounds__(256) void k_bh(const int* __restrict__ dst,
                                            int* __restrict__ bhist, int E) {
  __shared__ int lh[MAXBUK];
  int t = threadIdx.x;
  if (t < MAXBUK) lh[t] = 0;
  __syncthreads();
  for (int e = blockIdx.x * 256 + t; e < E; e += gridDim.x * 256)
    atomicAdd(&lh[dst[e] >> BSHIFT], 1);
  __syncthreads();
  if (t < MAXBUK && lh[t]) atomicAdd(&bhist[t], lh[t]);
}

// ---- stage 2: serial scan of <=256 bucket counts (trivial size)
__global__ __launch_bounds__(256) void k_bsc(const int* __restrict__ bhist,
                                             int* __restrict__ bbase,
                                             int* __restrict__ gcur,
                                             int* __restrict__ rowptr, int E, int N) {
  __shared__ int ls[MAXBUK];
  int t = threadIdx.x;
  ls[t] = bhist[t];
  __syncthreads();
  if (t == 0) {
    int run = 0;
    for (int i = 0; i < MAXBUK; ++i) {
      bbase[i] = run; gcur[i] = run; run += ls[i];
    }
    bbase[MAXBUK] = run;
    rowptr[N] = E;
  }
}

// ---- stage 3: partition packed (dl<<20)|src into bucket-grouped ebuf.
__global__ __launch_bounds__(256) void k_part(
    const int* __restrict__ src, const int* __restrict__ dst,
    int* __restrict__ gcur, uint* __restrict__ ebuf, int E) {
  __shared__ int lh[MAXBUK], lbase[MAXBUK], lcur[MAXBUK];
  int t = threadIdx.x;
  int base = blockIdx.x * PART_EPB;
  if (t < MAXBUK) lh[t] = 0;
  __syncthreads();
#pragma unroll 4
  for (int j = 0; j < PART_EPB / 256; ++j) {
    int e = base + j * 256 + t;
    if (e < E) atomicAdd(&lh[dst[e] >> BSHIFT], 1);
  }
  __syncthreads();
  if (t < MAXBUK) {
    lbase[t] = lh[t] ? atomicAdd(&gcur[t], lh[t]) : 0;
    lcur[t] = 0;
  }
  __syncthreads();
#pragma unroll 4
  for (int j = 0; j < PART_EPB / 256; ++j) {
    int e = base + j * 256 + t;
    if (e < E) {
      int d = dst[e];
      int b = d >> BSHIFT;
      int p = atomicAdd(&lcur[b], 1);
      ebuf[lbase[b] + p] = (uint)src[e] | ((uint)(d & (BNODES - 1)) << 20);
    }
  }
}

// ---- stage 4: one block per bucket: LDS hist -> scan -> rowptr/deg -> scatter
__global__ __launch_bounds__(256) void k_fill2(
    const uint* __restrict__ ebuf, const int* __restrict__ bbase,
    int* __restrict__ csrc, int* __restrict__ rowptr, int* __restrict__ deg, int N) {
  __shared__ int hcnt[BNODES];
  __shared__ int wls[4];
  int t = threadIdx.x;
  int b = blockIdx.x;
  int ebeg = bbase[b], eend = bbase[b + 1];
  for (int i = t; i < BNODES; i += 256) hcnt[i] = 0;
  __syncthreads();
  for (int e = ebeg + t; e < eend; e += 256)
    atomicAdd(&hcnt[ebuf[e] >> 20], 1);
  __syncthreads();
  const int PER = BNODES / 256;
  int lane = t & 63, wv = t >> 6;
  int x[PER]; int s = 0;
#pragma unroll
  for (int i = 0; i < PER; ++i) { x[i] = hcnt[PER * t + i]; s += x[i]; }
  int incl = s;
#pragma unroll
  for (int off = 1; off < 64; off <<= 1) {
    int u = __shfl_up(incl, off, 64);
    if (lane >= off) incl += u;
  }
  if (lane == 63) wls[wv] = incl;
  __syncthreads();
  int wbase = 0;
  for (int i = 0; i < wv; ++i) wbase += wls[i];
  int run = wbase + incl - s;
#pragma unroll
  for (int i = 0; i < PER; ++i) {
    int node = (b << BSHIFT) + PER * t + i;
    hcnt[PER * t + i] = run;
    if (node < N) { rowptr[node] = ebeg + run; deg[node] = x[i]; }
    run += x[i];
  }
  __syncthreads();
  for (int e = ebeg + t; e < eend; e += 256) {
    uint v = ebuf[e];
    int p = atomicAdd(&hcnt[v >> 20], 1);
    csrc[ebeg + p] = (int)(v & 0xFFFFFu);
  }
}

// ---- degree-sort: histogram -> scan -> scatter (LDS-aggregated, k_part
// pattern: one global atomic per (block,bucket), not per node — R11's
// per-node version serialized 100k atomics on 64 counters = 276us).
// Within-bucket order is atomic-arbitrary; per-node computation is
// order-independent -> output bit-identical.
__global__ __launch_bounds__(256) void k_dhist(const int* __restrict__ deg,
                                               int* __restrict__ dhist, int N) {
  __shared__ int lh[DBUK];
  int t = threadIdx.x;
  if (t < DBUK) lh[t] = 0;
  __syncthreads();
  for (int v = blockIdx.x * 256 + t; v < N; v += gridDim.x * 256)
    atomicAdd(&lh[min(deg[v], DBUK - 1)], 1);
  __syncthreads();
  if (t < DBUK && lh[t]) atomicAdd(&dhist[t], lh[t]);
}

__global__ __launch_bounds__(64) void k_dscan(const int* __restrict__ dhist,
                                              int* __restrict__ dcur) {
  if (threadIdx.x == 0) {
    int run = 0;
    for (int i = 0; i < DBUK; ++i) { dcur[i] = run; run += dhist[i]; }
  }
}

__global__ __launch_bounds__(256) void k_dscatter(
    const int* __restrict__ deg, const int* __restrict__ rowptr,
    int* __restrict__ dcur, int* __restrict__ orig2,
    int* __restrict__ beg2, int* __restrict__ deg2s, int N) {
  __shared__ int lh[DBUK], lbase[DBUK], lcur[DBUK];
  int t = threadIdx.x;
  int v = blockIdx.x * 256 + t;
  if (t < DBUK) lh[t] = 0;
  __syncthreads();
  int d = 0, b = 0;
  bool valid = v < N;
  if (valid) {
    d = deg[v];
    b = min(d, DBUK - 1);
    atomicAdd(&lh[b], 1);
  }
  __syncthreads();
  if (t < DBUK) {
    lbase[t] = lh[t] ? atomicAdd(&dcur[t], lh[t]) : 0;
    lcur[t] = 0;
  }
  __syncthreads();
  if (valid) {
    int p = atomicAdd(&lcur[b], 1);
    int k = lbase[b] + p;
    orig2[k] = v;
    beg2[k] = rowptr[v];
    deg2s[k] = d;
  }
}

// ---- m16[v] = bf16(m[v]) — the only nonzero column of h at t=0
__global__ void k_minit(const float* __restrict__ m, ushort* __restrict__ m16, int N) {
  int v = blockIdx.x * 256 + threadIdx.x;
  if (v < N) m16[v] = f2bf(m[v]);
}

// ---- step-0 gather: h rows are [m,0,...,0] so only dim 0 needs summing.
__global__ __launch_bounds__(256) void k_gather0(
    const int* __restrict__ rowptr, const int* __restrict__ csrc,
    const ushort* __restrict__ m16, ushort* __restrict__ hsum0, int N)
{
  int v = blockIdx.x * 256 + threadIdx.x;
  if (v >= N) return;
  int beg = rowptr[v], end = rowptr[v + 1];
  float a0 = 0.f, a1 = 0.f, a2 = 0.f, a3 = 0.f;
  int e = beg;
  for (; e + 16 <= end; e += 16) {
    a0 += (bf2f(m16[csrc[e + 0]]) + bf2f(m16[csrc[e + 4]])) +
          (bf2f(m16[csrc[e + 8]]) + bf2f(m16[csrc[e + 12]]));
    a1 += (bf2f(m16[csrc[e + 1]]) + bf2f(m16[csrc[e + 5]])) +
          (bf2f(m16[csrc[e + 9]]) + bf2f(m16[csrc[e + 13]]));
    a2 += (bf2f(m16[csrc[e + 2]]) + bf2f(m16[csrc[e + 6]])) +
          (bf2f(m16[csrc[e + 10]]) + bf2f(m16[csrc[e + 14]]));
    a3 += (bf2f(m16[csrc[e + 3]]) + bf2f(m16[csrc[e + 7]])) +
          (bf2f(m16[csrc[e + 11]]) + bf2f(m16[csrc[e + 15]]));
  }
  for (; e < end; e += 4) {
    if (e + 0 < end) a0 += bf2f(m16[csrc[e + 0]]);
    if (e + 1 < end) a1 += bf2f(m16[csrc[e + 1]]);
    if (e + 2 < end) a2 += bf2f(m16[csrc[e + 2]]);
    if (e + 3 < end) a3 += bf2f(m16[csrc[e + 3]]);
  }
  hsum0[v] = f2bf((a0 + a1) + (a2 + a3));
}

// ---- step-0 GRU: both GEMMs are rank-1 (only k=0 of A/H nonzero).
__global__ __launch_bounds__(256) void k_gru0(
    const ushort* __restrict__ hsum0, const ushort* __restrict__ m16,
    const int* __restrict__ deg,
    const ushort* __restrict__ Wc0, const ushort* __restrict__ Wh0,
    const float* __restrict__ bvec, const float* __restrict__ b_ih,
    const float* __restrict__ b_hh, ushort* __restrict__ hbn, int N)
{
  int idx = blockIdx.x * 256 + threadIdx.x;
  if (idx >= N * HID) return;
  int n = idx >> 7, d = idx & (HID - 1);
  float s0 = bf2f(hsum0[n]);
  float h0 = bf2f(m16[n]);
  float degf = (float)deg[n];
  float acc0 = s0 * bf2f(Wc0[d]);
  float acc1 = s0 * bf2f(Wc0[d + 128]);
  float acc2 = s0 * bf2f(Wc0[d + 256]);
  float acc3 = h0 * bf2f(Wh0[d]);
  float acc4 = h0 * bf2f(Wh0[d + 128]);
  float acc5 = h0 * bf2f(Wh0[d + 256]);
  float hold = (d == 0) ? h0 : 0.f;
  float ir = acc0 + degf * bvec[d] + b_ih[d];
  float iz = acc1 + degf * bvec[d + 128] + b_ih[d + 128];
  float in_ = acc2 + degf * bvec[d + 256] + b_ih[d + 256];
  float hr = acc3 + b_hh[d];
  float hz = acc4 + b_hh[d + 128];
  float hn = acc5 + b_hh[d + 256];
  float r = __builtin_amdgcn_rcpf(1.f + __expf(-(ir + hr)));
  float z = __builtin_amdgcn_rcpf(1.f + __expf(-(iz + hz)));
  float x2 = in_ + r * hn;
  float e2 = __expf(2.f * x2);
  float nv = 1.f - 2.f * __builtin_amdgcn_rcpf(e2 + 1.f);   // tanh
  float hv = (1.f - z) * nv + z * hold;
  hbn[idx] = f2bf(hv);
}

// ---- shared accumulate core (R8 semantics: 16-chunks tree + batched tail)
static __device__ __forceinline__ void accum_range(
    const ushort* __restrict__ hb, const int* __restrict__ csrc,
    int beg, int end, int g, int i, float acc[8])
{
  int e = beg;
  for (; e + 16 <= end; e += 16) {      // 16 edges in flight
    int s0 = csrc[e + g];
    int s1 = csrc[e + 4 + g];
    int s2 = csrc[e + 8 + g];
    int s3 = csrc[e + 12 + g];
    B8u w0; w0.u = *(const uint4*)(hb + (size_t)s0 * HID + i * 8);
    B8u w1; w1.u = *(const uint4*)(hb + (size_t)s1 * HID + i * 8);
    B8u w2; w2.u = *(const uint4*)(hb + (size_t)s2 * HID + i * 8);
    B8u w3; w3.u = *(const uint4*)(hb + (size_t)s3 * HID + i * 8);
#pragma unroll
    for (int j = 0; j < 8; ++j)
      acc[j] += (bf2f(w0.s[j]) + bf2f(w1.s[j])) + (bf2f(w2.s[j]) + bf2f(w3.s[j]));
  }
  int rem = end - e;                    // 0..15 -> batched predicated tail
  if (rem > 0) {
    int t0 = (g < rem)      ? csrc[e + g]      : -1;
    int t1 = (4 + g < rem)  ? csrc[e + 4 + g]  : -1;
    int t2 = (8 + g < rem)  ? csrc[e + 8 + g]  : -1;
    int t3 = (12 + g < rem) ? csrc[e + 12 + g] : -1;
    B8u r0, r1, r2, r3;
    if (t0 >= 0) r0.u = *(const uint4*)(hb + (size_t)t0 * HID + i * 8);
    if (t1 >= 0) r1.u = *(const uint4*)(hb + (size_t)t1 * HID + i * 8);
    if (t2 >= 0) r2.u = *(const uint4*)(hb + (size_t)t2 * HID + i * 8);
    if (t3 >= 0) r3.u = *(const uint4*)(hb + (size_t)t3 * HID + i * 8);
    if (t0 >= 0) {
#pragma unroll
      for (int j = 0; j < 8; ++j) acc[j] += bf2f(r0.s[j]);
    }
    if (t1 >= 0) {
#pragma unroll
      for (int j = 0; j < 8; ++j) acc[j] += bf2f(r1.s[j]);
    }
    if (t2 >= 0) {
#pragma unroll
      for (int j = 0; j < 8; ++j) acc[j] += bf2f(r2.s[j]);
    }
    if (t3 >= 0) {
#pragma unroll
      for (int j = 0; j < 8; ++j) acc[j] += bf2f(r3.s[j]);
    }
  }
}

// ---- gather one SORTED strip: slot k = strip*16 + w; meta loads coalesced
// and parallel, then csrc || hrow, then rows — same RT depth as R8, but all
// 16 waves have near-identical degree -> no barrier straggler.
static __device__ __forceinline__ void gather_strip_sorted(
    const int* __restrict__ beg2, const int* __restrict__ deg2s,
    const int* __restrict__ orig2, const int* __restrict__ csrc,
    const ushort* __restrict__ hb,
    int strip, int w, int lane, int N,
    ushort dstS[16][128], ushort dstH[16][128], int* dstDeg, int* dstOrig)
{
  int k = strip * 16 + w;
  if (k >= N) return;
  int g = lane >> 4;        // edge slot 0..3
  int i = lane & 15;        // 16B chunk of row
  int orig = orig2[k];
  int beg = beg2[k];
  int cnt = deg2s[k];
  if (g == 1)               // stage this node's h row (bit-identical copy)
    *(uint4*)(&dstH[w][(i ^ (w & 7)) * 8]) =
        *(const uint4*)(hb + (size_t)orig * HID + i * 8);
  if (lane == 0) dstOrig[w] = orig;
  if (lane == 32) dstDeg[w] = cnt;      // deg[v] == CSR row length
  float acc[8] = {0.f, 0.f, 0.f, 0.f, 0.f, 0.f, 0.f, 0.f};
  accum_range(hb, csrc, beg, beg + cnt, g, i, acc);
#pragma unroll
  for (int j = 0; j < 8; ++j) {
    acc[j] += __shfl_xor(acc[j], 16, 64);
    acc[j] += __shfl_xor(acc[j], 32, 64);
  }
  if (g == 0) {
    uint4 ov;
    ov.x = ((uint)f2bf(acc[1]) << 16) | (uint)f2bf(acc[0]);
    ov.y = ((uint)f2bf(acc[3]) << 16) | (uint)f2bf(acc[2]);
    ov.z = ((uint)f2bf(acc[5]) << 16) | (uint)f2bf(acc[4]);
    ov.w = ((uint)f2bf(acc[7]) << 16) | (uint)f2bf(acc[6]);
    *(uint4*)(&dstS[w][(i ^ (w & 7)) * 8]) = ov;
  }
}

// ==== k_fused (R8 structure + degree-sorted strips): gather + dual-GEMM +
// GRU per sorted strip; epilogue writes hbn[orig] -> bit-identical output.
__global__ __launch_bounds__(1024, 4) void k_fused(
    const int* __restrict__ beg2, const int* __restrict__ deg2s,
    const int* __restrict__ orig2, const int* __restrict__ csrc,
    const ushort* __restrict__ hbc, ushort* __restrict__ hbn,
    const ushort* __restrict__ Wcomb, const ushort* __restrict__ Whh16,
    const float* __restrict__ bvec, const float* __restrict__ b_ih,
    const float* __restrict__ b_hh, int N)
{
  __shared__ float S[6][16][132];        // 50688 B, +4 pad
  __shared__ ushort AT[3][2][16][128];   // 24576 B: [parity][0=gathersum,1=hrow]
  __shared__ int degT[3][16];
  __shared__ int origT[3][16];
  const int tid = threadIdx.x;
  const int w = tid >> 6;
  const int lane = tid & 63;
  const int quad = lane >> 4, l16 = lane & 15;
  const int gm = w >> 3;            // 0: W-path (gathersum x Wcomb), 1: H-path
  const int gw = w & 7;
  const int d0 = gw * 16;

  const ushort* Wmat = gm ? Whh16 : Wcomb;
  B8u bfr[3][4];
#pragma unroll
  for (int g = 0; g < 3; ++g)
#pragma unroll
    for (int kc = 0; kc < 4; ++kc) {
      int j = (d0 + g * 128 + l16) * HID + kc * 32 + quad * 8;
      bfr[g][kc].u = *(const uint4*)(Wmat + j);
    }

  const int ecol = tid & 127, erow0 = tid >> 7;
  const float bir = b_ih[ecol], biz = b_ih[ecol + 128], bin_ = b_ih[ecol + 256];
  const float bhr = b_hh[ecol], bhz = b_hh[ecol + 128], bhn = b_hh[ecol + 256];
  const float vr = bvec[ecol], vz = bvec[ecol + 128], vn = bvec[ecol + 256];

  const int nstrip = N >> 4;
  const int G = (int)gridDim.x;
  int s = blockIdx.x;
  if (s >= nstrip) return;

  gather_strip_sorted(beg2, deg2s, orig2, csrc, hbc, s, w, lane, N,
                      AT[0][0], AT[0][1], degT[0], origT[0]);
  asm volatile("s_waitcnt lgkmcnt(0)" ::: "memory");
  __builtin_amdgcn_sched_barrier(0);
  __builtin_amdgcn_s_barrier();

  int cur = 0;
  while (true) {
    int ns = s + G;
    bool more = ns < nstrip;
    int nxt = (cur == 2) ? 0 : cur + 1;
    if (more)   // prefetch-gather next strip; writes only parity 'nxt'
      gather_strip_sorted(beg2, deg2s, orig2, csrc, hbc, ns, w, lane, N,
                          AT[nxt][0], AT[nxt][1], degT[nxt], origT[nxt]);
    // A-fragments from LDS (chunk-swizzled; <=2-way bank alias = free)
    B8u af[4];
#pragma unroll
    for (int kc = 0; kc < 4; ++kc)
      af[kc].u = *(const uint4*)(&AT[cur][gm][l16][(((quad + 4 * kc) ^ (l16 & 7)) * 8)]);
    f32x4 acc[3] = {};
#pragma unroll
    for (int kc = 0; kc < 4; ++kc)
#pragma unroll
      for (int g = 0; g < 3; ++g)
        acc[g] = __builtin_amdgcn_mfma_f32_16x16x32_bf16(af[kc].b, bfr[g][kc].b, acc[g], 0, 0, 0);
    // (a) all waves past prev epilogue's S/AT[cur] reads -> safe to write S
    __builtin_amdgcn_s_barrier();
#pragma unroll
    for (int g = 0; g < 3; ++g)
#pragma unroll
      for (int rg = 0; rg < 4; ++rg)
        S[gm * 3 + g][quad * 4 + rg][d0 + l16] = acc[g][rg];
    // (b) drain own LDS ops (S writes + gather writes), leave vmcnt in flight
    asm volatile("s_waitcnt lgkmcnt(0)" ::: "memory");
    __builtin_amdgcn_sched_barrier(0);
    __builtin_amdgcn_s_barrier();
    int n0 = s << 4;
#pragma unroll
    for (int k = 0; k < 2; ++k) {
      int row = erow0 + 8 * k;
      float dgf = (float)degT[cur][row];
      int og = origT[cur][row];
      int sc = (((ecol >> 3) ^ (row & 7)) * 8) + (ecol & 7);
      float hold = bf2f(AT[cur][1][row][sc]);
      float ir  = S[0][row][ecol] + dgf * vr + bir;
      float iz  = S[1][row][ecol] + dgf * vz + biz;
      float in_ = S[2][row][ecol] + dgf * vn + bin_;
      float hr  = S[3][row][ecol] + bhr;
      float hz  = S[4][row][ecol] + bhz;
      float hn  = S[5][row][ecol] + bhn;
      float r = __builtin_amdgcn_rcpf(1.f + __expf(-(ir + hr)));
      float z = __builtin_amdgcn_rcpf(1.f + __expf(-(iz + hz)));
      float x2 = in_ + r * hn;
      float e2 = __expf(2.f * x2);
      float nv = 1.f - 2.f * __builtin_amdgcn_rcpf(e2 + 1.f);   // tanh
      float hv = (1.f - z) * nv + z * hold;
      if (n0 + row < N)
        hbn[(size_t)og * HID + ecol] = f2bf(hv);
    }
    if (!more) break;
    s = ns; cur = nxt;
  }
}

// ---- per-graph counts from SORTED gid: binary search, no atomics
__global__ __launch_bounds__(64) void k_bounds(const int* __restrict__ gid,
                                               int* __restrict__ cnt, int N, int G) {
  int g = threadIdx.x;
  if (g >= G) return;
  int lo = 0, hi = N;
  while (lo < hi) { int mid = (lo + hi) >> 1; if (gid[mid] < g) lo = mid + 1; else hi = mid; }
  int lb0 = lo;
  lo = 0; hi = N;
  int g1 = g + 1;
  while (lo < hi) { int mid = (lo + hi) >> 1; if (gid[mid] < g1) lo = mid + 1; else hi = mid; }
  cnt[g] = lo - lb0;
}

// ---- pooling: graph_ids sorted -> run-length accumulate, few atomics
#define POOL_CHUNK 96
__global__ __launch_bounds__(128) void k_pool(const ushort* __restrict__ hb,
                                              const int* __restrict__ gid,
                                              float* __restrict__ hg, int N) {
  int d = threadIdx.x;
  int start = blockIdx.x * POOL_CHUNK;
  if (start >= N) return;
  int end = min(start + POOL_CHUNK, N);
  float acc = 0.f;
  int g = gid[start];
  for (int n = start; n < end; ++n) {
    int gn = gid[n];
    if (gn != g) { unsafeAtomicAdd(&hg[g * HID + d], acc); acc = 0.f; g = gn; }
    acc += fmaxf(bf2f(hb[(size_t)n * HID + d]), 0.f);   // relu
  }
  unsafeAtomicAdd(&hg[g * HID + d], acc);
}

__global__ __launch_bounds__(640) void k_cls(const float* __restrict__ hg,
                                             const int* __restrict__ cnt,
                                             const float* __restrict__ Wc,
                                             const float* __restrict__ bc,
                                             float* __restrict__ out, int G) {
  int t = threadIdx.x;
  if (t >= G * 10) return;
  int g = t / 10, c = t % 10;
  float inv = 1.f / fmaxf((float)cnt[g], 1.f);
  float acc = 0.f;
  for (int d = 0; d < HID; ++d) acc = fmaf(hg[g * HID + d], Wc[c * HID + d], acc);
  out[t] = acc * inv + bc[c];
}

extern "C" void kernel_launch(void* const* d_in, const int* in_sizes, int n_in,
                              void* d_out, int out_size, void* d_ws, size_t ws_size,
                              hipStream_t stream) {
  const int N = in_sizes[0];
  const int E = in_sizes[9];
  const float* m    = (const float*)d_in[0];
  const float* W_e  = (const float*)d_in[1];
  const float* b_e  = (const float*)d_in[2];
  const float* W_ih = (const float*)d_in[3];
  const float* b_ih = (const float*)d_in[4];
  const float* W_hh = (const float*)d_in[5];
  const float* b_hh = (const float*)d_in[6];
  const float* W_cls = (const float*)d_in[7];
  const float* b_cls = (const float*)d_in[8];
  const int* src = (const int*)d_in[9];
  const int* dst = (const int*)d_in[10];
  const int* gid = (const int*)d_in[11];
  const int G = out_size / 10;
  float* out = (float*)d_out;

  size_t off = 0;
  auto alloc = [&](size_t b) {
    char* p = (char*)d_ws + off;
    off += (b + 255) & ~(size_t)255;
    return (void*)p;
  };
  ushort* hb0    = (ushort*)alloc((size_t)N * HID * 2);
  ushort* hb1    = (ushort*)alloc((size_t)N * HID * 2);
  int*    deg    = (int*)   alloc((size_t)N * 4);
  int*    rowptr = (int*)   alloc((size_t)(N + 1) * 4);
  int*    csrc   = (int*)   alloc((size_t)E * 4);
  uint*   ebuf   = (uint*)  alloc((size_t)E * 4);
  int*    bhist  = (int*)   alloc((size_t)MAXBUK * 4);
  int*    bbase  = (int*)   alloc((size_t)(MAXBUK + 1) * 4);
  int*    gcur   = (int*)   alloc((size_t)MAXBUK * 4);
  ushort* Wcomb  = (ushort*)alloc((size_t)G3 * HID * 2);
  ushort* Whh16  = (ushort*)alloc((size_t)G3 * HID * 2);
  float*  bvec   = (float*) alloc((size_t)G3 * 4);
  float*  hg     = (float*) alloc((size_t)G * HID * 4);
  int*    cnt    = (int*)   alloc((size_t)G * 4);
  ushort* m16    = (ushort*)alloc((size_t)N * 2);
  ushort* hsum0  = (ushort*)alloc((size_t)N * 2);
  ushort* Wc0    = (ushort*)alloc((size_t)G3 * 2);
  ushort* Wh0    = (ushort*)alloc((size_t)G3 * 2);
  int*    dhist  = (int*)   alloc((size_t)DBUK * 4);
  int*    dcur   = (int*)   alloc((size_t)DBUK * 4);
  int*    orig2  = (int*)   alloc((size_t)N * 4);
  int*    beg2   = (int*)   alloc((size_t)N * 4);
  int*    deg2s  = (int*)   alloc((size_t)N * 4);
  if (off > ws_size) return;   // workspace too small -> visible failure

  const int NBUK = (N + BNODES - 1) >> BSHIFT;   // 196 at N=100k (<= MAXBUK)

  k_weights<<<2 * G3, HID, 0, stream>>>(W_e, b_e, W_ih, W_hh, Wcomb, Whh16, bvec, Wc0, Wh0);
  k_minit<<<(N + 255) / 256, 256, 0, stream>>>(m, m16, N);
  hipMemsetAsync(bhist, 0, (size_t)MAXBUK * 4, stream);
  k_bh<<<256, 256, 0, stream>>>(dst, bhist, E);
  k_bsc<<<1, MAXBUK, 0, stream>>>(bhist, bbase, gcur, rowptr, E, N);
  k_part<<<(E + PART_EPB - 1) / PART_EPB, 256, 0, stream>>>(src, dst, gcur, ebuf, E);
  k_fill2<<<NBUK, 256, 0, stream>>>(ebuf, bbase, csrc, rowptr, deg, N);

  // ---- degree-sort the node processing order (one-time, LDS-aggregated)
  hipMemsetAsync(dhist, 0, (size_t)DBUK * 4, stream);
  k_dhist<<<64, 256, 0, stream>>>(deg, dhist, N);
  k_dscan<<<1, 64, 0, stream>>>(dhist, dcur);
  k_dscatter<<<(N + 255) / 256, 256, 0, stream>>>(deg, rowptr, dcur, orig2, beg2, deg2s, N);

  // ---- step 0: h = [m,0,...,0] is rank-1 -> scalar gather + rank-1 GRU
  k_gather0<<<(N + 255) / 256, 256, 0, stream>>>(rowptr, csrc, m16, hsum0, N);
  k_gru0<<<(N * HID + 255) / 256, 256, 0, stream>>>(hsum0, m16, deg, Wc0, Wh0,
                                                    bvec, b_ih, b_hh, hb1, N);

  ushort* hbc = hb1;
  ushort* hbn = hb0;
  const int nstrip = N >> 4;
  const int fuse_blocks = nstrip < 256 ? nstrip : 256;   // 1 block/CU (R8 best)
  for (int s = 1; s < TSTEPS; ++s) {
    k_fused<<<fuse_blocks, 1024, 0, stream>>>(beg2, deg2s, orig2, csrc, hbc, hbn,
                                              Wcomb, Whh16, bvec, b_ih, b_hh, N);
    ushort* t = hbc; hbc = hbn; hbn = t;
  }

  hipMemsetAsync(hg, 0, (size_t)G * HID * 4, stream);
  k_bounds<<<1, 64, 0, stream>>>(gid, cnt, N, G);
  k_pool<<<(N + POOL_CHUNK - 1) / POOL_CHUNK, HID, 0, stream>>>(hbc, gid, hg, N);
  k_cls<<<1, 640, 0, stream>>>(hg, cnt, W_cls, b_cls, out, G);
}